// Round 1
// baseline (510.078 us; speedup 1.0000x reference)
//
#include <hip/hip_runtime.h>
#include <math.h>

#define B_   4096
#define N_   64
#define HID_ 256
#define NH_  8
#define HD_  32
#define INV_SQRT_HD 0.17677669529663687f

// ============================ Kernel 1 ======================================
// 512 blocks x 256 threads; block handles 8 rows of h_recv.
// Outputs: qh_ws[B][8][256], b1_ws[B][8] (softplus MLP), konst_ws[B][8] (pre-scaled)
__global__ __launch_bounds__(256, 2) void k1_proj(
    const float* __restrict__ h_recv,
    const float* __restrict__ wq_w, const float* __restrict__ wq_b,
    const float* __restrict__ wk_w, const float* __restrict__ wk_b,
    const float* __restrict__ d1_w, const float* __restrict__ d1_b,
    const float* __restrict__ d2_w, const float* __restrict__ d2_b,
    float* __restrict__ qh_ws, float* __restrict__ b1_ws, float* __restrict__ konst_ws)
{
    __shared__ __align__(16) float hr[8][256];
    __shared__ __align__(16) float Q[8][256];
    __shared__ float R1[8][128];
    const int t = threadIdx.x;
    const int brow = blockIdx.x * 8;

    // stage 8 rows of h_recv (512 float4)
    {
        const float4* src = (const float4*)(h_recv + (size_t)brow * 256);
        float4* dst = (float4*)&hr[0][0];
        dst[t] = src[t];
        dst[t + 256] = src[t + 256];
    }
    __syncthreads();

    // Phase A: Q[bb][j], j = t, all 8 rows
    {
        const int j = t;
        float acc[8];
        const float bq = wq_b[j];
#pragma unroll
        for (int bb = 0; bb < 8; bb++) acc[bb] = bq;
        for (int c4 = 0; c4 < 64; c4++) {
            const float w0 = wq_w[(c4 * 4 + 0) * 256 + j];
            const float w1 = wq_w[(c4 * 4 + 1) * 256 + j];
            const float w2 = wq_w[(c4 * 4 + 2) * 256 + j];
            const float w3 = wq_w[(c4 * 4 + 3) * 256 + j];
#pragma unroll
            for (int bb = 0; bb < 8; bb++) {
                const float4 h = *(const float4*)&hr[bb][c4 * 4];
                acc[bb] += h.x * w0 + h.y * w1 + h.z * w2 + h.w * w3;
            }
        }
#pragma unroll
        for (int bb = 0; bb < 8; bb++) Q[bb][j] = acc[bb];
    }
    __syncthreads();

    // Phase B: R1 = relu(h_recv @ d1 + d1_b), [8][128]
    {
        const int j = t & 127;
        const int bg = t >> 7;          // 0..1 -> rows bg*4..bg*4+3
        float acc[4];
        const float bd = d1_b[j];
#pragma unroll
        for (int r = 0; r < 4; r++) acc[r] = bd;
        for (int c4 = 0; c4 < 64; c4++) {
            const float w0 = d1_w[(c4 * 4 + 0) * 128 + j];
            const float w1 = d1_w[(c4 * 4 + 1) * 128 + j];
            const float w2 = d1_w[(c4 * 4 + 2) * 128 + j];
            const float w3 = d1_w[(c4 * 4 + 3) * 128 + j];
#pragma unroll
            for (int r = 0; r < 4; r++) {
                const float4 h = *(const float4*)&hr[bg * 4 + r][c4 * 4];
                acc[r] += h.x * w0 + h.y * w1 + h.z * w2 + h.w * w3;
            }
        }
#pragma unroll
        for (int r = 0; r < 4; r++) R1[bg * 4 + r][j] = fmaxf(acc[r], 0.0f);
    }
    __syncthreads();

    // Phase C (t<64): MLP head + softplus, and the wk_b constant (pre-scaled)
    if (t < 64) {
        const int bb = t >> 3, h = t & 7;
        float acc = d2_b[h];
        for (int jj = 0; jj < 128; jj++) acc += R1[bb][jj] * d2_w[jj * 8 + h];
        const float sp = (acc > 20.0f) ? acc : log1pf(expf(acc));
        b1_ws[(size_t)(brow + bb) * 8 + h] = sp;
        float k = 0.0f;
        for (int d = 0; d < 32; d++) k += Q[bb][h * 32 + d] * wk_b[h * 32 + d];
        konst_ws[(size_t)(brow + bb) * 8 + h] = k * INV_SQRT_HD;
    }

    // Phase D: qh[bb][h][c] = sum_d Q[bb][h*32+d] * wk[c][h*32+d]; c = t
    {
        const int c = t;
        for (int h = 0; h < 8; h++) {
            float acc[8] = {0, 0, 0, 0, 0, 0, 0, 0};
#pragma unroll
            for (int d4 = 0; d4 < 8; d4++) {
                const float4 w = *(const float4*)&wk_w[(size_t)c * 256 + h * 32 + d4 * 4];
#pragma unroll
                for (int bb = 0; bb < 8; bb++) {
                    const float4 q = *(const float4*)&Q[bb][h * 32 + d4 * 4];
                    acc[bb] += q.x * w.x + q.y * w.y + q.z * w.z + q.w * w.w;
                }
            }
#pragma unroll
            for (int bb = 0; bb < 8; bb++)
                qh_ws[((size_t)(brow + bb) * 8 + h) * 256 + c] = acc[bb];
        }
    }
}

// ============================ Kernel 2 ======================================
// One block (256 thr) per batch element. LDS ~77.8 KB -> 2 blocks/CU.
template <bool ZIN>
__global__ __launch_bounds__(256, 2) void k2_attn(
    const float* __restrict__ h_send,
    const float* __restrict__ dist, const int* __restrict__ mask,
    const float* __restrict__ qh_ws, const float* __restrict__ b1_ws,
    const float* __restrict__ konst_ws,
    float* __restrict__ attn_out,          // [B][64][8]
    float* __restrict__ ctx_ws,            // [B][8][256] (primary path)
    const float* __restrict__ wv_w, const float* __restrict__ wv_b,
    float* __restrict__ z_out)             // [B][256] (fallback path)
{
    __shared__ __align__(16) float hs[64][260];   // padded: wave b128 reads bank-even
    __shared__ __align__(16) float qh[8][260];
    __shared__ float sc[64][9];
    __shared__ float dist_l[64];
    __shared__ float b1_l[8], kon_l[8];
    __shared__ int mask_l[64];

    const int t = threadIdx.x;
    const int b = blockIdx.x;
    const int w = t >> 6;
    const int l = t & 63;

    // ---- stage h_send[b] (64KB) + qh[b] (8KB) + small vectors ----
    {
        const float4* src = (const float4*)(h_send + (size_t)b * 16384);
#pragma unroll
        for (int i = 0; i < 16; i++) {
            const int q = t + 256 * i;
            *(float4*)&hs[q >> 6][(q & 63) * 4] = src[q];
        }
        const float4* qsrc = (const float4*)(qh_ws + (size_t)b * 2048);
        {
            int q = t;
            *(float4*)&qh[q >> 6][(q & 63) * 4] = qsrc[q];
            q = t + 256;
            *(float4*)&qh[q >> 6][(q & 63) * 4] = qsrc[q];
        }
        if (t < 64) {
            dist_l[t] = dist[(size_t)b * 64 + t];
            mask_l[t] = mask[(size_t)b * 64 + t];
        } else if (t < 72) {
            b1_l[t - 64] = b1_ws[(size_t)b * 8 + (t - 64)];
            kon_l[t - 64] = konst_ws[(size_t)b * 8 + (t - 64)];
        }
    }
    __syncthreads();

    // ---- scores: wave w owns n = w*16 + (l&15); lanes split c into quarters ----
    {
        const int n = w * 16 + (l & 15);
        const int cq = l >> 4;             // c-quarter 0..3
        float p[8] = {0, 0, 0, 0, 0, 0, 0, 0};
#pragma unroll 4
        for (int c4 = 0; c4 < 16; c4++) {
            const int cc = cq * 64 + c4 * 4;
            const float4 hv = *(const float4*)&hs[n][cc];
#pragma unroll
            for (int h = 0; h < 8; h++) {
                const float4 qv = *(const float4*)&qh[h][cc];
                p[h] += hv.x * qv.x + hv.y * qv.y + hv.z * qv.z + hv.w * qv.w;
            }
        }
#pragma unroll
        for (int h = 0; h < 8; h++) {       // reduce the 4 c-quarters (lanes l^16,l^32)
            p[h] += __shfl_xor(p[h], 16, 64);
            p[h] += __shfl_xor(p[h], 32, 64);
        }
        if (cq == 0) {
            const float dv = dist_l[n];
            const int mv = mask_l[n];
#pragma unroll
            for (int h = 0; h < 8; h++) {
                const float s = p[h] * INV_SQRT_HD + kon_l[h] - b1_l[h] * dv;
                sc[n][h] = mv ? s : -1e30f;
            }
        }
    }
    __syncthreads();

    // ---- softmax over n per head: wave w handles h = 2w + l/32 ----
    {
        const int h = 2 * w + (l >> 5);
        const int n0 = l & 31;
        const float v0 = sc[n0][h], v1 = sc[n0 + 32][h];
        float m = fmaxf(v0, v1);
#pragma unroll
        for (int s = 1; s < 32; s <<= 1) m = fmaxf(m, __shfl_xor(m, s, 64));
        const float e0 = __expf(v0 - m), e1 = __expf(v1 - m);
        float sum = e0 + e1;
#pragma unroll
        for (int s = 1; s < 32; s <<= 1) sum += __shfl_xor(sum, s, 64);
        const float inv = 1.0f / sum;
        sc[n0][h] = e0 * inv;
        sc[n0 + 32][h] = e1 * inv;
    }
    __syncthreads();

    // ---- write attn output (coalesced) ----
    {
        attn_out[(size_t)b * 512 + t] = sc[t >> 3][t & 7];
        attn_out[(size_t)b * 512 + t + 256] = sc[(t + 256) >> 3][t & 7];
    }

    // ---- ctx[h][c] = sum_n attn[n][h] * hs[n][c]; accumulated in registers ----
    {
        const int h = t >> 5;
        const int l32 = t & 31;
        float4 a0 = make_float4(0.f, 0.f, 0.f, 0.f);
        float4 a1 = make_float4(0.f, 0.f, 0.f, 0.f);
        for (int n = 0; n < 64; n++) {
            const float at = sc[n][h];
            const float4 h0 = *(const float4*)&hs[n][4 * l32];
            const float4 h1 = *(const float4*)&hs[n][4 * l32 + 128];
            a0.x += at * h0.x; a0.y += at * h0.y; a0.z += at * h0.z; a0.w += at * h0.w;
            a1.x += at * h1.x; a1.y += at * h1.y; a1.z += at * h1.z; a1.w += at * h1.w;
        }
        if (!ZIN) {
            float4* co = (float4*)(ctx_ws + ((size_t)b * 8 + h) * 256);
            co[l32] = a0;
            co[l32 + 32] = a1;
        } else {
            *(float4*)&qh[h][4 * l32] = a0;         // reuse qh buffer as ctx
            *(float4*)&qh[h][4 * l32 + 128] = a1;
        }
    }

    if (ZIN) {   // fallback: z GEMM inline (wv from L2)
        __syncthreads();
        const int j = t;
        const int h = j >> 5;
        float acc = wv_b[j];
        for (int c4 = 0; c4 < 64; c4++) {
            const float4 cv = *(const float4*)&qh[h][c4 * 4];
            acc += cv.x * wv_w[(c4 * 4 + 0) * 256 + j] + cv.y * wv_w[(c4 * 4 + 1) * 256 + j]
                 + cv.z * wv_w[(c4 * 4 + 2) * 256 + j] + cv.w * wv_w[(c4 * 4 + 3) * 256 + j];
        }
        z_out[(size_t)b * 256 + j] = acc;
    }
}

// ============================ Kernel 3 ======================================
// z = ctx @ wv (per head 32-col slice) + wv_b.  512 blocks x 256 thr, 8 rows each.
__global__ __launch_bounds__(256, 2) void k3_z(
    const float* __restrict__ ctx_ws, const float* __restrict__ wv_w,
    const float* __restrict__ wv_b, float* __restrict__ z_out)
{
    const int t = threadIdx.x;
    const int tj = t & 63, tb = t >> 6;
    const int j0 = tj * 4;
    const int h = tj >> 3;                 // = j0/32
    const int b0 = blockIdx.x * 8 + tb * 2;
    const int b1r = b0 + 1;

    const float4 bias = *(const float4*)&wv_b[j0];
    float4 a0 = bias, a1 = bias;
    const float* c0p = ctx_ws + ((size_t)b0 * 8 + h) * 256;
    const float* c1p = ctx_ws + ((size_t)b1r * 8 + h) * 256;
    for (int c4 = 0; c4 < 64; c4++) {
        const float4 x0 = *(const float4*)&c0p[c4 * 4];
        const float4 x1 = *(const float4*)&c1p[c4 * 4];
        const float4 w0 = *(const float4*)&wv_w[(c4 * 4 + 0) * 256 + j0];
        const float4 w1 = *(const float4*)&wv_w[(c4 * 4 + 1) * 256 + j0];
        const float4 w2 = *(const float4*)&wv_w[(c4 * 4 + 2) * 256 + j0];
        const float4 w3 = *(const float4*)&wv_w[(c4 * 4 + 3) * 256 + j0];
        a0.x += x0.x * w0.x + x0.y * w1.x + x0.z * w2.x + x0.w * w3.x;
        a0.y += x0.x * w0.y + x0.y * w1.y + x0.z * w2.y + x0.w * w3.y;
        a0.z += x0.x * w0.z + x0.y * w1.z + x0.z * w2.z + x0.w * w3.z;
        a0.w += x0.x * w0.w + x0.y * w1.w + x0.z * w2.w + x0.w * w3.w;
        a1.x += x1.x * w0.x + x1.y * w1.x + x1.z * w2.x + x1.w * w3.x;
        a1.y += x1.x * w0.y + x1.y * w1.y + x1.z * w2.y + x1.w * w3.y;
        a1.z += x1.x * w0.z + x1.y * w1.z + x1.z * w2.z + x1.w * w3.z;
        a1.w += x1.x * w0.w + x1.y * w1.w + x1.z * w2.w + x1.w * w3.w;
    }
    *(float4*)&z_out[(size_t)b0 * 256 + j0] = a0;
    *(float4*)&z_out[(size_t)b1r * 256 + j0] = a1;
}

// ============================ Launch ========================================
extern "C" void kernel_launch(void* const* d_in, const int* in_sizes, int n_in,
                              void* d_out, int out_size, void* d_ws, size_t ws_size,
                              hipStream_t stream)
{
    const float* h_recv = (const float*)d_in[0];
    const float* h_send = (const float*)d_in[1];
    const float* dist   = (const float*)d_in[2];
    const int*   mask   = (const int*)d_in[3];
    const float* wq_w = (const float*)d_in[4];
    const float* wq_b = (const float*)d_in[5];
    const float* wk_w = (const float*)d_in[6];
    const float* wk_b = (const float*)d_in[7];
    const float* wv_w = (const float*)d_in[8];
    const float* wv_b = (const float*)d_in[9];
    const float* d1_w = (const float*)d_in[10];
    const float* d1_b = (const float*)d_in[11];
    const float* d2_w = (const float*)d_in[12];
    const float* d2_b = (const float*)d_in[13];

    float* z_out = (float*)d_out;                              // [B][256]
    float* attn_out = (float*)d_out + (size_t)B_ * HID_;       // [B][64][8]

    float* ws = (float*)d_ws;
    const size_t QH = (size_t)B_ * 8 * 256;                    // 8M floats
    const size_t need_primary = (QH * 2 + (size_t)B_ * 8 * 2) * sizeof(float);
    const bool primary = ws_size >= need_primary;

    float* qh_ws = ws;
    size_t off = QH;
    float* ctx_ws = nullptr;
    if (primary) { ctx_ws = ws + off; off += QH; }
    float* b1_ws = ws + off; off += (size_t)B_ * 8;
    float* konst_ws = ws + off;

    k1_proj<<<512, 256, 0, stream>>>(h_recv, wq_w, wq_b, wk_w, wk_b,
                                     d1_w, d1_b, d2_w, d2_b,
                                     qh_ws, b1_ws, konst_ws);
    if (primary) {
        k2_attn<false><<<B_, 256, 0, stream>>>(h_send, dist, mask, qh_ws, b1_ws, konst_ws,
                                               attn_out, ctx_ws, wv_w, wv_b, z_out);
        k3_z<<<512, 256, 0, stream>>>(ctx_ws, wv_w, wv_b, z_out);
    } else {
        k2_attn<true><<<B_, 256, 0, stream>>>(h_send, dist, mask, qh_ws, b1_ws, konst_ws,
                                              attn_out, nullptr, wv_w, wv_b, z_out);
    }
}